// Round 1
// baseline (31360.373 us; speedup 1.0000x reference)
//
#include <hip/hip_runtime.h>
#include <cstdint>
#include <cstddef>

// LSTM: T=512, B=64, E=1024, H=1024, fp32.
// Phase 1: Xproj[t][g][r][b] = bias_g[r] + sum_e Wx_g[r][e]*emb[t][b][e]  (big GEMM)
// Phase 2: per-step kernel: pre = Xproj + Wh_g @ h_{t-1}; gates; c,h update.
// h_t stored directly in d_out (out[t] is the [H,B] slab). c state in ws tail.

#define TT 512
#define BB 64
#define EE 1024
#define HH 1024

// ---------------------------------------------------------------------------
// Phase 1: C[m][n] = sum_k W4[m][k] * emb[n][k] + bias4[m]
// M=4096 (4 gates x 1024 rows), N = nt*64 (chunk of timesteps), K=1024.
// 128x128 tile per 256-thread block, 8x8 micro-tile, K-chunk = 8.
// grid = (32 m-tiles, nt/2 n-tiles)   [nt forced even by host]
// ---------------------------------------------------------------------------
__global__ __launch_bounds__(256)
void lstm_xproj_kernel(const float* __restrict__ emb,
                       const float* __restrict__ Wgx, const float* __restrict__ Wix,
                       const float* __restrict__ Wfx, const float* __restrict__ Wox,
                       const float* __restrict__ bg,  const float* __restrict__ bi,
                       const float* __restrict__ bfv, const float* __restrict__ bo,
                       float* __restrict__ xp, int row0)
{
    __shared__ float As[8][128];
    __shared__ float Bs[8][128];

    const int tid = threadIdx.x;
    const int m0 = blockIdx.x * 128;            // row tile (within 4096)
    const int n0 = blockIdx.y * 128;            // col tile (chunk-local n = tloc*64+b)
    const int gate = m0 >> 10;
    const int r0 = m0 & 1023;

    const float* __restrict__ W    = (gate == 0) ? Wgx : (gate == 1) ? Wix : (gate == 2) ? Wfx : Wox;
    const float* __restrict__ bias = (gate == 0) ? bg  : (gate == 1) ? bi  : (gate == 2) ? bfv : bo;

    const int li = tid >> 1;                    // 0..127 : row within tile for loads
    const int lq = (tid & 1) * 4;               // 0 or 4 : k-slot
    const int mi = (tid & 15) * 8;              // micro-tile row base
    const int ni = (tid >> 4) * 8;              // micro-tile col base

    const float* aptr = W   + (size_t)(r0 + li) * EE + lq;
    const float* bptr = emb + (size_t)(row0 + n0 + li) * EE + lq;

    float acc[8][8];
    #pragma unroll
    for (int p = 0; p < 8; ++p)
        #pragma unroll
        for (int q = 0; q < 8; ++q) acc[p][q] = 0.f;

    for (int k0 = 0; k0 < EE; k0 += 8) {
        float4 av = *(const float4*)(aptr + k0);
        float4 bv = *(const float4*)(bptr + k0);
        __syncthreads();
        As[lq + 0][li] = av.x; As[lq + 1][li] = av.y; As[lq + 2][li] = av.z; As[lq + 3][li] = av.w;
        Bs[lq + 0][li] = bv.x; Bs[lq + 1][li] = bv.y; Bs[lq + 2][li] = bv.z; Bs[lq + 3][li] = bv.w;
        __syncthreads();
        #pragma unroll
        for (int kk = 0; kk < 8; ++kk) {
            float a[8], b[8];
            *(float4*)&a[0] = *(const float4*)&As[kk][mi];
            *(float4*)&a[4] = *(const float4*)&As[kk][mi + 4];
            *(float4*)&b[0] = *(const float4*)&Bs[kk][ni];
            *(float4*)&b[4] = *(const float4*)&Bs[kk][ni + 4];
            #pragma unroll
            for (int p = 0; p < 8; ++p)
                #pragma unroll
                for (int q = 0; q < 8; ++q)
                    acc[p][q] += a[p] * b[q];
        }
    }

    // epilogue: xp[((tloc*4096) + m)*64 + b], n = n0 + ni + q, tloc = n>>6, b = n&63
    #pragma unroll
    for (int p = 0; p < 8; ++p) {
        const int m = m0 + mi + p;
        const float bval = bias[r0 + mi + p];
        #pragma unroll
        for (int q0 = 0; q0 < 8; q0 += 4) {
            const int n = n0 + ni + q0;
            const int tloc = n >> 6;
            const int b = n & 63;
            float4 v = make_float4(acc[p][q0] + bval, acc[p][q0 + 1] + bval,
                                   acc[p][q0 + 2] + bval, acc[p][q0 + 3] + bval);
            *(float4*)&xp[((size_t)tloc * 4096 + m) * 64 + b] = v;
        }
    }
}

// ---------------------------------------------------------------------------
// Phase 2: one timestep. 256 blocks x 512 threads.
// thread: b = tid&63, rloc = (tid>>6)&3, kh = tid>>8 (K split in 2).
// Computes all 4 gate dots for cell (r,b); LDS reduce across kh; elementwise.
// ---------------------------------------------------------------------------
__device__ __forceinline__ float sigmoid_f(float x) { return 1.f / (1.f + __expf(-x)); }
__device__ __forceinline__ float tanh_f(float x) {
    x = fminf(12.f, fmaxf(-12.f, x));
    float e = __expf(2.f * x);
    return (e - 1.f) / (e + 1.f);
}

__global__ __launch_bounds__(512)
void lstm_step_kernel(const float* __restrict__ Wgh, const float* __restrict__ Wih,
                      const float* __restrict__ Wfh, const float* __restrict__ Woh,
                      const float* __restrict__ xp,     // this step's [4][1024][64] slab
                      const float* __restrict__ hprev,  // out + (t-1)*H*B (unused if first)
                      float* __restrict__ hout,         // out + t*H*B
                      float* __restrict__ cstate,
                      int first)
{
    const int tid = threadIdx.x;
    const int b = tid & 63;
    const int rloc = (tid >> 6) & 3;
    const int kh = tid >> 8;                     // 0 or 1
    const int r = blockIdx.x * 4 + rloc;
    const int ru = __builtin_amdgcn_readfirstlane(r);   // wave-uniform row

    float ag = 0.f, ai = 0.f, af = 0.f, ao = 0.f;
    if (!first) {
        const float* __restrict__ wg = Wgh + (size_t)ru * HH;
        const float* __restrict__ wi = Wih + (size_t)ru * HH;
        const float* __restrict__ wf = Wfh + (size_t)ru * HH;
        const float* __restrict__ wo = Woh + (size_t)ru * HH;
        const float* __restrict__ hp = hprev + b;
        const int kbeg = kh * 512, kend = kbeg + 512;
        #pragma unroll 4
        for (int k = kbeg; k < kend; k += 4) {
            float4 g4 = *(const float4*)(wg + k);
            float4 i4 = *(const float4*)(wi + k);
            float4 f4 = *(const float4*)(wf + k);
            float4 o4 = *(const float4*)(wo + k);
            float h0 = hp[(k + 0) * 64];
            float h1 = hp[(k + 1) * 64];
            float h2 = hp[(k + 2) * 64];
            float h3 = hp[(k + 3) * 64];
            ag += g4.x * h0 + g4.y * h1 + g4.z * h2 + g4.w * h3;
            ai += i4.x * h0 + i4.y * h1 + i4.z * h2 + i4.w * h3;
            af += f4.x * h0 + f4.y * h1 + f4.z * h2 + f4.w * h3;
            ao += o4.x * h0 + o4.y * h1 + o4.z * h2 + o4.w * h3;
        }
    }

    __shared__ float red[4][4][64];              // [rloc][gate][b]
    if (kh) {
        red[rloc][0][b] = ag; red[rloc][1][b] = ai;
        red[rloc][2][b] = af; red[rloc][3][b] = ao;
    }
    __syncthreads();
    if (!kh) {
        ag += red[rloc][0][b]; ai += red[rloc][1][b];
        af += red[rloc][2][b]; ao += red[rloc][3][b];

        const int idx = r * 64 + b;
        float pg = xp[(0 * 1024 + r) * 64 + b] + ag;
        float pi = xp[(1 * 1024 + r) * 64 + b] + ai;
        float pf = xp[(2 * 1024 + r) * 64 + b] + af;
        float po = xp[(3 * 1024 + r) * 64 + b] + ao;

        float g  = tanh_f(pg);
        float ii = sigmoid_f(pi);
        float ff = sigmoid_f(pf);
        float oo = sigmoid_f(po);
        float c  = first ? 0.f : cstate[idx];
        float cn = g * ii + c * ff;
        cstate[idx] = cn;
        hout[idx] = tanh_f(cn) * oo;
    }
}

// ---------------------------------------------------------------------------
extern "C" void kernel_launch(void* const* d_in, const int* in_sizes, int n_in,
                              void* d_out, int out_size, void* d_ws, size_t ws_size,
                              hipStream_t stream)
{
    const float* emb = (const float*)d_in[0];
    const float* Wgx = (const float*)d_in[1];
    const float* Wgh = (const float*)d_in[2];
    const float* Wix = (const float*)d_in[3];
    const float* Wih = (const float*)d_in[4];
    const float* Wfx = (const float*)d_in[5];
    const float* Wfh = (const float*)d_in[6];
    const float* Wox = (const float*)d_in[7];
    const float* Woh = (const float*)d_in[8];
    const float* bg  = (const float*)d_in[9];
    const float* bi  = (const float*)d_in[10];
    const float* bfv = (const float*)d_in[11];
    const float* bo  = (const float*)d_in[12];
    float* out = (float*)d_out;
    char*  ws  = (char*)d_ws;

    const size_t per_t  = (size_t)4 * HH * BB * sizeof(float);   // 1 MiB per timestep
    const size_t cbytes = (size_t)HH * BB * sizeof(float);       // 256 KiB c-state

    int Tc;
    if (ws_size >= per_t * TT + cbytes) {
        Tc = TT;
    } else {
        size_t avail = (ws_size > cbytes + 4096) ? (ws_size - cbytes - 4096) : 2 * per_t;
        Tc = (int)(avail / per_t);
        Tc &= ~1;                 // even so every phase-1 n-tile (128 cols = 2 steps) is full
        if (Tc < 2) Tc = 2;       // minimum footprint ~2.3 MiB
    }

    float* xp     = (float*)ws;
    float* cstate = (float*)(ws + (size_t)Tc * per_t);

    for (int tc0 = 0; tc0 < TT; tc0 += Tc) {
        const int nt = (TT - tc0 < Tc) ? (TT - tc0) : Tc;   // even (Tc even, TT even)
        dim3 g1(32, nt / 2);
        lstm_xproj_kernel<<<g1, 256, 0, stream>>>(emb, Wgx, Wix, Wfx, Wox,
                                                  bg, bi, bfv, bo, xp, tc0 * 64);
        for (int t = tc0; t < tc0 + nt; ++t) {
            const float* hprev = (t == 0) ? out : out + (size_t)(t - 1) * HH * BB;
            lstm_step_kernel<<<dim3(256), dim3(512), 0, stream>>>(
                Wgh, Wih, Wfh, Woh,
                xp + (size_t)(t - tc0) * 4 * HH * BB,
                hprev,
                out + (size_t)t * HH * BB,
                cstate,
                (t == 0) ? 1 : 0);
        }
    }
}

// Round 2
// 15088.805 us; speedup vs baseline: 2.0784x; 2.0784x over previous
//
#include <hip/hip_runtime.h>
#include <cstdint>
#include <cstddef>

// LSTM: T=512, B=64, E=1024, H=1024, fp32.
// Phase 1: Xproj[t][g][r][b] = bias_g[r] + sum_e Wx_g[r][e]*emb[t][b][e]  (big GEMM)
// Phase 2: per-step kernel: pre = Xproj + Wh_g @ h_{t-1}; gates; c,h update.
//   R2 change: recurrent weights staged into LDS (64 KB/block) and read as
//   wave-uniform ds_read_b128 broadcasts; R1 read them as 64-lane same-address
//   global vector loads, which choked the TA pipe (~55 us/step).
// h_t stored directly in d_out (out[t] is the [H,B] slab). c state in ws tail.

#define TT 512
#define BB 64
#define EE 1024
#define HH 1024

// ---------------------------------------------------------------------------
// Phase 1: C[m][n] = sum_k W4[m][k] * emb[n][k] + bias4[m]
// M=4096 (4 gates x 1024 rows), N = nt*64 (chunk of timesteps), K=1024.
// 128x128 tile per 256-thread block, 8x8 micro-tile, K-chunk = 8.
// grid = (32 m-tiles, nt/2 n-tiles)   [nt forced even by host]
// ---------------------------------------------------------------------------
__global__ __launch_bounds__(256)
void lstm_xproj_kernel(const float* __restrict__ emb,
                       const float* __restrict__ Wgx, const float* __restrict__ Wix,
                       const float* __restrict__ Wfx, const float* __restrict__ Wox,
                       const float* __restrict__ bg,  const float* __restrict__ bi,
                       const float* __restrict__ bfv, const float* __restrict__ bo,
                       float* __restrict__ xp, int row0)
{
    __shared__ float As[8][128];
    __shared__ float Bs[8][128];

    const int tid = threadIdx.x;
    const int m0 = blockIdx.x * 128;            // row tile (within 4096)
    const int n0 = blockIdx.y * 128;            // col tile (chunk-local n = tloc*64+b)
    const int gate = m0 >> 10;
    const int r0 = m0 & 1023;

    const float* __restrict__ W    = (gate == 0) ? Wgx : (gate == 1) ? Wix : (gate == 2) ? Wfx : Wox;
    const float* __restrict__ bias = (gate == 0) ? bg  : (gate == 1) ? bi  : (gate == 2) ? bfv : bo;

    const int li = tid >> 1;                    // 0..127 : row within tile for loads
    const int lq = (tid & 1) * 4;               // 0 or 4 : k-slot
    const int mi = (tid & 15) * 8;              // micro-tile row base
    const int ni = (tid >> 4) * 8;              // micro-tile col base

    const float* aptr = W   + (size_t)(r0 + li) * EE + lq;
    const float* bptr = emb + (size_t)(row0 + n0 + li) * EE + lq;

    float acc[8][8];
    #pragma unroll
    for (int p = 0; p < 8; ++p)
        #pragma unroll
        for (int q = 0; q < 8; ++q) acc[p][q] = 0.f;

    for (int k0 = 0; k0 < EE; k0 += 8) {
        float4 av = *(const float4*)(aptr + k0);
        float4 bv = *(const float4*)(bptr + k0);
        __syncthreads();
        As[lq + 0][li] = av.x; As[lq + 1][li] = av.y; As[lq + 2][li] = av.z; As[lq + 3][li] = av.w;
        Bs[lq + 0][li] = bv.x; Bs[lq + 1][li] = bv.y; Bs[lq + 2][li] = bv.z; Bs[lq + 3][li] = bv.w;
        __syncthreads();
        #pragma unroll
        for (int kk = 0; kk < 8; ++kk) {
            float a[8], b[8];
            *(float4*)&a[0] = *(const float4*)&As[kk][mi];
            *(float4*)&a[4] = *(const float4*)&As[kk][mi + 4];
            *(float4*)&b[0] = *(const float4*)&Bs[kk][ni];
            *(float4*)&b[4] = *(const float4*)&Bs[kk][ni + 4];
            #pragma unroll
            for (int p = 0; p < 8; ++p)
                #pragma unroll
                for (int q = 0; q < 8; ++q)
                    acc[p][q] += a[p] * b[q];
        }
    }

    // epilogue: xp[((tloc*4096) + m)*64 + b], n = n0 + ni + q, tloc = n>>6, b = n&63
    #pragma unroll
    for (int p = 0; p < 8; ++p) {
        const int m = m0 + mi + p;
        const float bval = bias[r0 + mi + p];
        #pragma unroll
        for (int q0 = 0; q0 < 8; q0 += 4) {
            const int n = n0 + ni + q0;
            const int tloc = n >> 6;
            const int b = n & 63;
            float4 v = make_float4(acc[p][q0] + bval, acc[p][q0 + 1] + bval,
                                   acc[p][q0 + 2] + bval, acc[p][q0 + 3] + bval);
            *(float4*)&xp[((size_t)tloc * 4096 + m) * 64 + b] = v;
        }
    }
}

// ---------------------------------------------------------------------------
// Phase 2: one timestep. 256 blocks x 512 threads (8 waves).
// thread: b = tid&63 (lane), rloc = (tid>>6)&3, kh = tid>>8 (K split in 2).
// Block stages Wh rows [r0..r0+3] x 4 gates x 1024 k into 64 KB LDS
// (coalesced global dwordx4), then each wave reads its weights as
// wave-uniform ds_read_b128 (LDS broadcast, conflict-free). h loads stay
// global & lane-coalesced (256 B/instr). kh-reduction scratch is aliased
// into the upper-k half of each wave's own LDS rows, which that wave has
// already finished reading (kh1 reads k in [512,1024) then writes there;
// kh0 only ever reads k in [0,512)).
// ---------------------------------------------------------------------------
__device__ __forceinline__ float sigmoid_f(float x) { return 1.f / (1.f + __expf(-x)); }
__device__ __forceinline__ float tanh_f(float x) {
    x = fminf(12.f, fmaxf(-12.f, x));
    float e = __expf(2.f * x);
    return (e - 1.f) / (e + 1.f);
}

__global__ __launch_bounds__(512)
void lstm_step_kernel(const float* __restrict__ Wgh, const float* __restrict__ Wih,
                      const float* __restrict__ Wfh, const float* __restrict__ Woh,
                      const float* __restrict__ xp,     // this step's [4][1024][64] slab
                      const float* __restrict__ hprev,  // out + (t-1)*H*B (unused if first)
                      float* __restrict__ hout,         // out + t*H*B
                      float* __restrict__ cstate,
                      int first)
{
    __shared__ float lds[16 * 1024];             // exactly 64 KB: lds[row][k], row = rloc*4+gate

    const int tid = threadIdx.x;
    const int b = tid & 63;
    const int rloc = (tid >> 6) & 3;
    const int kh = tid >> 8;                     // 0 or 1
    const int r0 = blockIdx.x * 4;
    const int r = r0 + rloc;

    float ag = 0.f, ai = 0.f, af = 0.f, ao = 0.f;

    if (!first) {
        // ---- stage weights: 16 rows x 1024 floats = 4096 float4, 8 iters ----
        #pragma unroll
        for (int it = 0; it < 8; ++it) {
            const int idx = tid + it * 512;      // float4 index, 0..4095
            const int row = idx >> 8;            // 0..15 (256 float4 per row)
            const int rl = row >> 2;
            const int g = row & 3;
            const int k4 = idx & 255;
            const float* __restrict__ src =
                ((g == 0) ? Wgh : (g == 1) ? Wih : (g == 2) ? Wfh : Woh)
                + (size_t)(r0 + rl) * HH + k4 * 4;
            *(float4*)&lds[row * 1024 + k4 * 4] = *(const float4*)src;
        }
        __syncthreads();

        // ---- recurrent dot: 4 gates x 512 k per wave ----
        const float* __restrict__ hp = hprev + b;
        const float* wg = &lds[(rloc * 4 + 0) * 1024];
        const float* wi = &lds[(rloc * 4 + 1) * 1024];
        const float* wf = &lds[(rloc * 4 + 2) * 1024];
        const float* wo = &lds[(rloc * 4 + 3) * 1024];
        const int kbeg = kh * 512, kend = kbeg + 512;
        #pragma unroll 2
        for (int k = kbeg; k < kend; k += 4) {
            float4 g4 = *(const float4*)&wg[k];
            float4 i4 = *(const float4*)&wi[k];
            float4 f4 = *(const float4*)&wf[k];
            float4 o4 = *(const float4*)&wo[k];
            float h0 = hp[(k + 0) * 64];
            float h1 = hp[(k + 1) * 64];
            float h2 = hp[(k + 2) * 64];
            float h3 = hp[(k + 3) * 64];
            ag += g4.x * h0 + g4.y * h1 + g4.z * h2 + g4.w * h3;
            ai += i4.x * h0 + i4.y * h1 + i4.z * h2 + i4.w * h3;
            af += f4.x * h0 + f4.y * h1 + f4.z * h2 + f4.w * h3;
            ao += o4.x * h0 + o4.y * h1 + o4.z * h2 + o4.w * h3;
        }
    }

    // ---- kh reduction via aliased LDS (upper-k half of own rows) ----
    // red(rloc, g, b) lives at lds[(rloc*4+g)*1024 + 512 + b]
    if (kh) {
        lds[(rloc * 4 + 0) * 1024 + 512 + b] = ag;
        lds[(rloc * 4 + 1) * 1024 + 512 + b] = ai;
        lds[(rloc * 4 + 2) * 1024 + 512 + b] = af;
        lds[(rloc * 4 + 3) * 1024 + 512 + b] = ao;
    }
    __syncthreads();
    if (!kh) {
        ag += lds[(rloc * 4 + 0) * 1024 + 512 + b];
        ai += lds[(rloc * 4 + 1) * 1024 + 512 + b];
        af += lds[(rloc * 4 + 2) * 1024 + 512 + b];
        ao += lds[(rloc * 4 + 3) * 1024 + 512 + b];

        const int idx = r * 64 + b;
        float pg = xp[(0 * 1024 + r) * 64 + b] + ag;
        float pi = xp[(1 * 1024 + r) * 64 + b] + ai;
        float pf = xp[(2 * 1024 + r) * 64 + b] + af;
        float po = xp[(3 * 1024 + r) * 64 + b] + ao;

        float g  = tanh_f(pg);
        float ii = sigmoid_f(pi);
        float ff = sigmoid_f(pf);
        float oo = sigmoid_f(po);
        float c  = first ? 0.f : cstate[idx];
        float cn = g * ii + c * ff;
        cstate[idx] = cn;
        hout[idx] = tanh_f(cn) * oo;
    }
}

// ---------------------------------------------------------------------------
extern "C" void kernel_launch(void* const* d_in, const int* in_sizes, int n_in,
                              void* d_out, int out_size, void* d_ws, size_t ws_size,
                              hipStream_t stream)
{
    const float* emb = (const float*)d_in[0];
    const float* Wgx = (const float*)d_in[1];
    const float* Wgh = (const float*)d_in[2];
    const float* Wix = (const float*)d_in[3];
    const float* Wih = (const float*)d_in[4];
    const float* Wfx = (const float*)d_in[5];
    const float* Wfh = (const float*)d_in[6];
    const float* Wox = (const float*)d_in[7];
    const float* Woh = (const float*)d_in[8];
    const float* bg  = (const float*)d_in[9];
    const float* bi  = (const float*)d_in[10];
    const float* bfv = (const float*)d_in[11];
    const float* bo  = (const float*)d_in[12];
    float* out = (float*)d_out;
    char*  ws  = (char*)d_ws;

    const size_t per_t  = (size_t)4 * HH * BB * sizeof(float);   // 1 MiB per timestep
    const size_t cbytes = (size_t)HH * BB * sizeof(float);       // 256 KiB c-state

    int Tc;
    if (ws_size >= per_t * TT + cbytes) {
        Tc = TT;
    } else {
        size_t avail = (ws_size > cbytes + 4096) ? (ws_size - cbytes - 4096) : 2 * per_t;
        Tc = (int)(avail / per_t);
        Tc &= ~1;                 // even so every phase-1 n-tile (128 cols = 2 steps) is full
        if (Tc < 2) Tc = 2;       // minimum footprint ~2.3 MiB
    }

    float* xp     = (float*)ws;
    float* cstate = (float*)(ws + (size_t)Tc * per_t);

    for (int tc0 = 0; tc0 < TT; tc0 += Tc) {
        const int nt = (TT - tc0 < Tc) ? (TT - tc0) : Tc;   // even (Tc even, TT even)
        dim3 g1(32, nt / 2);
        lstm_xproj_kernel<<<g1, 256, 0, stream>>>(emb, Wgx, Wix, Wfx, Wox,
                                                  bg, bi, bfv, bo, xp, tc0 * 64);
        for (int t = tc0; t < tc0 + nt; ++t) {
            const float* hprev = (t == 0) ? out : out + (size_t)(t - 1) * HH * BB;
            lstm_step_kernel<<<dim3(256), dim3(512), 0, stream>>>(
                Wgh, Wih, Wfh, Woh,
                xp + (size_t)(t - tc0) * 4 * HH * BB,
                hprev,
                out + (size_t)t * HH * BB,
                cstate,
                (t == 0) ? 1 : 0);
        }
    }
}